// Round 2
// baseline (236.955 us; speedup 1.0000x reference)
//
#include <hip/hip_runtime.h>
#include <hip/hip_bf16.h>
#include <math.h>

// Problem constants
#define NM 1024         // molecules
#define NA 32           // atoms per molecule
#define ZD 64           // z dim
#define HD 256          // hidden
#define AT 10           // atom types
#define BT 5            // bond types
#define NROWS (NM*NA)   // 32768
#define EPM 496         // edges per molecule (C(32,2))
#define ATOM_OUT (NROWS*AT)  // 327680

// ---------------------------------------------------------------------------
// K1: Gram matrix M = Z^T Z (64x64) and column sums of Z.
// Grid 64 x 256 threads; each block accumulates 512 rows in 4 chunks of 128
// through one 32KB LDS tile, then does 16+1 fp32 atomics per thread.
// (vs. previous 256-block version: 4x fewer global atomics, same FLOPs)
// ---------------------------------------------------------------------------
__global__ __launch_bounds__(256) void k1_moments(const float* __restrict__ z,
                                                  float* __restrict__ Msum,
                                                  float* __restrict__ sumz) {
    __shared__ __align__(16) float zs[128][64];   // 32 KB
    __shared__ float sred[4][64];
    const int tid = threadIdx.x;
    const int d0 = (tid >> 4) << 2;               // 0..60
    const int e0 = (tid & 15) << 2;
    const int d = tid & 63, rq = tid >> 6;
    float acc[4][4] = {};
    float colsum = 0.f;
    for (int chunk = 0; chunk < 4; ++chunk) {
        const int rowbase = (blockIdx.x * 4 + chunk) * 128;
        __syncthreads();                          // protect zs reuse across chunks
        for (int k = 0; k < 32; ++k) {
            int idx = tid + (k << 8);             // 0..8191
            zs[idx >> 6][idx & 63] = z[rowbase * 64 + idx];
        }
        __syncthreads();
        for (int r = 0; r < 128; ++r) {
            float4 a4 = *(const float4*)&zs[r][d0];
            float4 b4 = *(const float4*)&zs[r][e0];
            float a[4] = {a4.x, a4.y, a4.z, a4.w};
            float b[4] = {b4.x, b4.y, b4.z, b4.w};
            #pragma unroll
            for (int i = 0; i < 4; ++i)
                #pragma unroll
                for (int jj = 0; jj < 4; ++jj) acc[i][jj] += a[i] * b[jj];
        }
        for (int r = rq * 32; r < rq * 32 + 32; ++r) colsum += zs[r][d];
    }
    #pragma unroll
    for (int i = 0; i < 4; ++i)
        #pragma unroll
        for (int jj = 0; jj < 4; ++jj)
            atomicAdd(&Msum[(d0 + i) * 64 + (e0 + jj)], acc[i][jj]);
    sred[rq][d] = colsum;
    __syncthreads();
    if (tid < 64)
        atomicAdd(&sumz[tid], sred[0][tid] + sred[1][tid] + sred[2][tid] + sred[3][tid]);
}

// ---------------------------------------------------------------------------
// K2W: (a) blocks 0..63: fold BN into per-channel affine h_bn = (z@W1)*a + c.
//   meanraw_j = (sumz . W1_j)/N ; var_j = W1_j^T (M/N) W1_j - meanraw^2
//   a = gamma*rsqrt(var+eps) ; c = beta - meanraw*a    (b1 cancels exactly)
//   4 waves/block, one channel per wave.
// (b) blocks 64..143: Wsym[t] = 0.5*(B[t]+B[t]^T)  (20480 elems).
// ---------------------------------------------------------------------------
__global__ __launch_bounds__(256) void k2w(const float* __restrict__ Msum,
                                           const float* __restrict__ sumz,
                                           const float* __restrict__ W1,
                                           const float* __restrict__ gamma,
                                           const float* __restrict__ beta,
                                           const float* __restrict__ bond,
                                           float* __restrict__ avec,
                                           float* __restrict__ cvec,
                                           float* __restrict__ Wsym) {
    const int tid = threadIdx.x;
    if (blockIdx.x >= 64) {
        int idx = ((int)blockIdx.x - 64) * 256 + tid;   // 0..20479
        int t = idx >> 12, rem = idx & 4095, dd = rem >> 6, c = rem & 63;
        Wsym[idx] = 0.5f * (bond[(t << 12) + (dd << 6) + c] +
                            bond[(t << 12) + (c << 6) + dd]);
        return;
    }
    const int wv = tid >> 6, d = tid & 63;
    const int j = blockIdx.x * 4 + wv;                  // 0..255
    const float wdj = W1[d * HD + j];
    float v = 0.f;
    for (int e = 0; e < 64; ++e) v += Msum[d * 64 + e] * W1[e * HD + j];
    float q = v * wdj;
    float s = sumz[d] * wdj;
    #pragma unroll
    for (int off = 32; off >= 1; off >>= 1) {
        q += __shfl_down(q, off);
        s += __shfl_down(s, off);
    }
    if (d == 0) {
        const float invN = 1.f / (float)NROWS;
        float mean = s * invN;
        float var = q * invN - mean * mean;
        float a = gamma[j] * rsqrtf(var + 1e-5f);
        avec[j] = a;
        cvec[j] = beta[j] - mean * a;
    }
}

// ---------------------------------------------------------------------------
// K3: fused MLP: atom_types = gelu((z@W1)*a + c) @ W2 + b2
// 512 blocks x 64 rows, 256 threads. Thread tile: 4 rows x 16 channels.
// GEMM2 partials reduced across 16 channel-groups via shfl_xor (lanes 0..15).
// ---------------------------------------------------------------------------
__global__ __launch_bounds__(256) void k3_mlp(const float* __restrict__ z,
                                              const float* __restrict__ W1,
                                              const float* __restrict__ W2,
                                              const float* __restrict__ b2,
                                              const float* __restrict__ avec,
                                              const float* __restrict__ cvec,
                                              float* __restrict__ out_atom) {
    __shared__ __align__(16) float zsT[64][68];   // [d][row], padded (272B rows, 16B-aligned)
    __shared__ __align__(16) float w1s[16][256];  // one 16-d chunk of W1
    __shared__ __align__(16) float w2s[256][10];
    __shared__ float as[256], cs[256];
    const int tid = threadIdx.x;
    const int rowbase = blockIdx.x * 64;
    for (int k = 0; k < 16; ++k) {
        int idx = tid + (k << 8);                 // 0..4095
        int r = idx >> 6, d = idx & 63;
        zsT[d][r] = z[(rowbase + r) * 64 + d];
    }
    for (int k = tid; k < HD * AT; k += 256) ((float*)w2s)[k] = W2[k];
    as[tid] = avec[tid]; cs[tid] = cvec[tid];

    const int rg = tid >> 4, cg = tid & 15;
    const int r0 = rg << 2;
    float acc[4][4][4] = {};                      // [row][cblock][u]
    for (int ch = 0; ch < 4; ++ch) {
        __syncthreads();                          // w1s reuse (and zsT/w2s staging on ch=0)
        for (int k = 0; k < 16; ++k) {
            int idx = tid + (k << 8);
            w1s[idx >> 8][idx & 255] = W1[(ch << 12) + idx];
        }
        __syncthreads();
        #pragma unroll
        for (int dl = 0; dl < 16; ++dl) {
            float4 zv = *(const float4*)&zsT[(ch << 4) + dl][r0];
            float zr[4] = {zv.x, zv.y, zv.z, zv.w};
            #pragma unroll
            for (int cb = 0; cb < 4; ++cb) {
                float4 wv = *(const float4*)&w1s[dl][(cb << 6) + (cg << 2)];
                float wr[4] = {wv.x, wv.y, wv.z, wv.w};
                #pragma unroll
                for (int ri = 0; ri < 4; ++ri)
                    #pragma unroll
                    for (int u = 0; u < 4; ++u) acc[ri][cb][u] += zr[ri] * wr[u];
            }
        }
    }
    // epilogue: affine + exact gelu + GEMM2 partials
    float p[4][10] = {};
    #pragma unroll
    for (int cb = 0; cb < 4; ++cb)
        #pragma unroll
        for (int u = 0; u < 4; ++u) {
            const int c = (cb << 6) + (cg << 2) + u;
            const float a = as[c], cc = cs[c];
            #pragma unroll
            for (int ri = 0; ri < 4; ++ri) {
                float h = acc[ri][cb][u] * a + cc;
                h = 0.5f * h * (1.0f + erff(h * 0.70710678118654752f));
                #pragma unroll
                for (int o = 0; o < 10; ++o) p[ri][o] += h * w2s[c][o];
            }
        }
    #pragma unroll
    for (int m = 1; m <= 8; m <<= 1)
        #pragma unroll
        for (int ri = 0; ri < 4; ++ri)
            #pragma unroll
            for (int o = 0; o < 10; ++o) p[ri][o] += __shfl_xor(p[ri][o], m);
    if (cg == 0) {
        #pragma unroll
        for (int ri = 0; ri < 4; ++ri)
            for (int o = 0; o < 10; ++o)
                out_atom[(rowbase + r0 + ri) * AT + o] = p[ri][o] + b2[o];
    }
}

// ---------------------------------------------------------------------------
// K4: edges. Block = 2 molecules, 256 threads, 512 blocks.
// Phase A (per d-half): u[t][d][j] = sum_c Wsym[t][d][c]*z_j[c]; W symmetry ->
//   read Wsym[t][c][d0..d0+7] rows (contiguous, wave-uniform -> s_loads).
//   Lanes = 2 mol x 32 j ; waves own 8-d ranges (uniform via readfirstlane).
// Phase B: logits[i][j][t] += z_i[d-chunk] . u[t][d-chunk][j], tile 4i x 2j x 5t.
// Then per-thread softmax over t and direct global write (edge_index is the
// deterministic combinations order; the input index tensor is not needed).
// ---------------------------------------------------------------------------
__global__ __launch_bounds__(256) void k4_edges(const float* __restrict__ z,
                                                const float* __restrict__ Wsym,
                                                float* __restrict__ out_edge) {
    __shared__ __align__(16) float zs[2][32][68];       // 17.4 KB
    __shared__ __align__(16) float uT[2][5][32][36];    // [mol][t][j][dlocal] 46 KB
    const int tid = threadIdx.x;
    const int gmol0 = blockIdx.x * 2;
    for (int k = 0; k < 16; ++k) {
        int idx = tid + (k << 8);                       // 0..4095
        int ml = idx >> 11, rem = idx & 2047, j = rem >> 6, c = rem & 63;
        zs[ml][j][c] = z[((gmol0 + ml) * 32 + j) * 64 + c];
    }
    // B-phase ids
    const int molB = tid >> 7, tid7 = tid & 127;
    const int i0 = (tid7 >> 4) << 2;                    // 4-row tile
    const int j0 = (tid7 & 15) << 1;                    // 2-col tile
    float accE[5][4][2] = {};
    // A-phase ids
    const int wv = __builtin_amdgcn_readfirstlane(tid >> 6);  // wave id (uniform)
    const int lane = tid & 63;
    const int molA = lane >> 5, jA = lane & 31;
    __syncthreads();

    for (int dh = 0; dh < 2; ++dh) {
        const int d0 = dh * 32 + wv * 8;                // uniform base of this wave's 8 d's
        #pragma unroll
        for (int t = 0; t < 5; ++t) {
            float accA[8] = {};
            for (int cc = 0; cc < 16; ++cc) {
                float4 z4 = *(const float4*)&zs[molA][jA][cc << 2];
                float zr[4] = {z4.x, z4.y, z4.z, z4.w};
                #pragma unroll
                for (int k = 0; k < 4; ++k) {
                    const int c = (cc << 2) + k;
                    const float* wp = Wsym + ((t << 6) + c) * 64 + d0;  // uniform -> s_load
                    #pragma unroll
                    for (int dd = 0; dd < 8; ++dd) accA[dd] += wp[dd] * zr[k];
                }
            }
            #pragma unroll
            for (int dd = 0; dd < 8; ++dd) uT[molA][t][jA][wv * 8 + dd] = accA[dd];
        }
        __syncthreads();
        for (int q = 0; q < 8; ++q) {                   // 8 chunks of 4 d within this half
            const int gd = dh * 32 + (q << 2);
            float zch[4][4];
            #pragma unroll
            for (int ri = 0; ri < 4; ++ri) {
                float4 zv = *(const float4*)&zs[molB][i0 + ri][gd];
                zch[ri][0] = zv.x; zch[ri][1] = zv.y; zch[ri][2] = zv.z; zch[ri][3] = zv.w;
            }
            #pragma unroll
            for (int t = 0; t < 5; ++t)
                #pragma unroll
                for (int rj = 0; rj < 2; ++rj) {
                    float4 uv = *(const float4*)&uT[molB][t][j0 + rj][q << 2];
                    float ur[4] = {uv.x, uv.y, uv.z, uv.w};
                    #pragma unroll
                    for (int ri = 0; ri < 4; ++ri)
                        #pragma unroll
                        for (int dd = 0; dd < 4; ++dd)
                            accE[t][ri][rj] += zch[ri][dd] * ur[dd];
                }
        }
        __syncthreads();
    }
    // softmax over 5 types + write (combinations order, i < j)
    const int ebase = (gmol0 + molB) * EPM;
    #pragma unroll
    for (int ri = 0; ri < 4; ++ri)
        #pragma unroll
        for (int rj = 0; rj < 2; ++rj) {
            int i = i0 + ri, j = j0 + rj;
            if (i < j) {
                float l0 = accE[0][ri][rj], l1 = accE[1][ri][rj], l2 = accE[2][ri][rj];
                float l3 = accE[3][ri][rj], l4 = accE[4][ri][rj];
                float m = fmaxf(fmaxf(fmaxf(l0, l1), fmaxf(l2, l3)), l4);
                float e0 = expf(l0 - m), e1 = expf(l1 - m), e2 = expf(l2 - m);
                float e3 = expf(l3 - m), e4 = expf(l4 - m);
                float inv = 1.0f / (e0 + e1 + e2 + e3 + e4);
                int p = 31 * i - ((i * (i - 1)) >> 1) + (j - i - 1);
                float* o = out_edge + (ebase + p) * 5;
                o[0] = e0 * inv; o[1] = e1 * inv; o[2] = e2 * inv;
                o[3] = e3 * inv; o[4] = e4 * inv;
            }
        }
}

// ---------------------------------------------------------------------------
extern "C" void kernel_launch(void* const* d_in, const int* in_sizes, int n_in,
                              void* d_out, int out_size, void* d_ws, size_t ws_size,
                              hipStream_t stream) {
    (void)in_sizes; (void)n_in; (void)out_size; (void)ws_size;
    const float* z     = (const float*)d_in[0];
    const float* W1    = (const float*)d_in[1];
    // d_in[2] = b1 : cancels exactly in BN -> unused
    const float* gamma = (const float*)d_in[3];
    const float* beta  = (const float*)d_in[4];
    const float* W2    = (const float*)d_in[5];
    const float* b2    = (const float*)d_in[6];
    const float* bond  = (const float*)d_in[7];
    // d_in[8] = edge_index : deterministic combinations order, recomputed -> unused
    float* out = (float*)d_out;
    float* ws  = (float*)d_ws;

    float* Msum = ws;              // 4096
    float* sumz = ws + 4096;       // 64
    float* avec = ws + 4160;       // 256
    float* cvec = ws + 4416;       // 256
    float* Wsym = ws + 4672;       // 20480  (total ~100 KB of ws)

    hipMemsetAsync(ws, 0, (4096 + 64) * sizeof(float), stream);
    k1_moments<<<64, 256, 0, stream>>>(z, Msum, sumz);
    k2w<<<144, 256, 0, stream>>>(Msum, sumz, W1, gamma, beta, bond, avec, cvec, Wsym);
    k3_mlp<<<512, 256, 0, stream>>>(z, W1, W2, b2, avec, cvec, out);
    k4_edges<<<512, 256, 0, stream>>>(z, Wsym, out + ATOM_OUT);
}